// Round 3
// baseline (193.397 us; speedup 1.0000x reference)
//
#include <hip/hip_runtime.h>
#include <stdint.h>

// ---- problem constants ----
constexpr int Mdim = 8192;
constexpr int Ndim = 4096;
constexpr int Kdim = 4096;
constexpr int NT = Kdim / 128;  // 32 K-tiles of BK=128

#define ISF        ((float)(2.0 / 255.0))          // IN_SCALE
#define OUT_SCALE  ((float)(2.0 / 255.0 * 0.01))   // IN_SCALE * W_SCALE
#define BSCALE     0.01f
// IN_ZP = 127 (the +1e-12 pulls 127.5 below the .5 boundary). x_shifted in [-127,128]
// doesn't fit int8 -> compute u = x_q - 128 in [-128,127]; acc = GEMM(u,w) + rowsum_w[n].

typedef int i32x4 __attribute__((ext_vector_type(4)));
typedef int i32x16 __attribute__((ext_vector_type(16)));

// ---------------- pre-pass 1: quantize x_float -> int8 (u = clip(round(x/s+127),0,255)-128)
__global__ __launch_bounds__(256) void quantize_x(const float* __restrict__ x,
                                                  int* __restrict__ x8,
                                                  int ngroups) {
  int idx = blockIdx.x * 256 + threadIdx.x;
  int stride = gridDim.x * 256;
  for (int g = idx; g < ngroups; g += stride) {
    float4 v = reinterpret_cast<const float4*>(x)[g];
    int a0 = (int)rintf(v.x / ISF + 127.0f);
    int a1 = (int)rintf(v.y / ISF + 127.0f);
    int a2 = (int)rintf(v.z / ISF + 127.0f);
    int a3 = (int)rintf(v.w / ISF + 127.0f);
    a0 = a0 < 0 ? 0 : (a0 > 255 ? 255 : a0); a0 -= 128;
    a1 = a1 < 0 ? 0 : (a1 > 255 ? 255 : a1); a1 -= 128;
    a2 = a2 < 0 ? 0 : (a2 > 255 ? 255 : a2); a2 -= 128;
    a3 = a3 < 0 ? 0 : (a3 > 255 ? 255 : a3); a3 -= 128;
    x8[g] = (a0 & 0xff) | ((a1 & 0xff) << 8) | ((a2 & 0xff) << 16) |
            (int)(((unsigned)(a3 & 0xff)) << 24);
  }
}

// ---------------- pre-pass 2: w_q int32 -> int8 packed, fused per-row sum
__global__ __launch_bounds__(256) void convert_w(const int* __restrict__ wq,
                                                 int* __restrict__ w8,
                                                 int* __restrict__ wsum) {
  int row = blockIdx.x;
  const int4* src = reinterpret_cast<const int4*>(wq + (size_t)row * Kdim);
  int* dst = w8 + (size_t)row * (Kdim / 4);
  int s = 0;
#pragma unroll
  for (int i = 0; i < 4; ++i) {
    int idx = i * 256 + threadIdx.x;
    int4 v = src[idx];
    s += v.x + v.y + v.z + v.w;
    dst[idx] = (v.x & 0xff) | ((v.y & 0xff) << 8) | ((v.z & 0xff) << 16) |
               (int)(((unsigned)(v.w & 0xff)) << 24);
  }
  __shared__ int red[256];
  red[threadIdx.x] = s;
  __syncthreads();
  for (int off = 128; off; off >>= 1) {
    if ((int)threadIdx.x < off) red[threadIdx.x] += red[threadIdx.x + off];
    __syncthreads();
  }
  if (threadIdx.x == 0) wsum[row] = red[0];
}

// ---------------- 256x256 i8 GEMM, mfma_i32_32x32x32, 4-phase/K-tile, counted vmcnt
// LDS: A buf0 @0, A buf1 @32768, B buf0 @65536, B buf1 @98304  (128 KiB)
#define AS1C const __attribute__((address_space(1))) void*
#define AS3  __attribute__((address_space(3))) void*
#define GLL(src, dst) __builtin_amdgcn_global_load_lds((AS1C)(src), (AS3)(dst), 16, 0, 0)
#define BAR() asm volatile("s_barrier" ::: "memory")
#define MFMA32(a, b, c) __builtin_amdgcn_mfma_i32_32x32x32_i8(a, b, c, 0, 0, 0)

__global__ __launch_bounds__(512, 2) void gemm_i8_32(const int8_t* __restrict__ A8,
                                                     const int8_t* __restrict__ B8,
                                                     const int* __restrict__ wsum,
                                                     const int* __restrict__ bq,
                                                     float* __restrict__ out) {
  __shared__ uint8_t lds[131072];

  // bijective XCD swizzle: 512 blocks, 512 % 8 == 0
  int bid = blockIdx.x;
  int wg = (bid & 7) * 64 + (bid >> 3);
  int bm = wg >> 4;  // 32 row-tiles
  int bn = wg & 15;  // 16 col-tiles

  const int tid = threadIdx.x;
  const int lane = tid & 63;
  const int wv = tid >> 6;   // 0..7
  const int wr = wv >> 2;    // 0..1 : 128-row half of C
  const int wc = wv & 3;     // 0..3 : 64-col quarter of C
  const int l31 = lane & 31, hi1 = lane >> 5;
  const int sw = l31 & 7;

  // staging source (per lane): row-chunk r3, slot s3, pre-swizzled col (rule #21)
  const int r3 = lane >> 3, s3 = lane & 7;
  const int swcol = (s3 ^ r3) << 4;
  const size_t aoff = (size_t)(bm * 256 + wv * 8 + r3) * Kdim + swcol;
  const size_t boff = (size_t)(bn * 256 + wv * 8 + r3) * Kdim + swcol;
  const int ldsw = wv * 1024;

#define ISSUE_A(P, t, half) do { \
    GLL(A8 + aoff + (size_t)(t) * 128 + (size_t)((half) * 128) * Kdim, \
        &lds[(P) * 32768 + (half) * 16384 + ldsw]); \
    GLL(A8 + aoff + (size_t)(t) * 128 + (size_t)((half) * 128 + 64) * Kdim, \
        &lds[(P) * 32768 + (half) * 16384 + 8192 + ldsw]); \
  } while (0)
#define ISSUE_B(P, t, half) do { \
    GLL(B8 + boff + (size_t)(t) * 128 + (size_t)((half) * 128) * Kdim, \
        &lds[65536 + (P) * 32768 + (half) * 16384 + ldsw]); \
    GLL(B8 + boff + (size_t)(t) * 128 + (size_t)((half) * 128 + 64) * Kdim, \
        &lds[65536 + (P) * 32768 + (half) * 16384 + 8192 + ldsw]); \
  } while (0)

  // fragment addressing: A row = wr*128 + ri*32 + l31, k-slot = (ks*2 + hi1) ^ (row&7)
  int arow[4], brow[2], sl[4];
#pragma unroll
  for (int ri = 0; ri < 4; ++ri) arow[ri] = (wr * 128 + ri * 32 + l31) * 128;
#pragma unroll
  for (int cj = 0; cj < 2; ++cj) brow[cj] = (wc * 64 + cj * 32 + l31) * 128;
#pragma unroll
  for (int ks = 0; ks < 4; ++ks) sl[ks] = ((ks * 2 + hi1) ^ sw) << 4;

#define LDA(P, ri, ks) (*reinterpret_cast<const i32x4*>(&lds[(P) * 32768 + arow[ri] + sl[ks]]))
#define LDB(P, cj, ks) (*reinterpret_cast<const i32x4*>(&lds[65536 + (P) * 32768 + brow[cj] + sl[ks]]))

  i32x16 acc[4][2];
#pragma unroll
  for (int i = 0; i < 4; ++i)
#pragma unroll
    for (int j = 0; j < 2; ++j)
#pragma unroll
      for (int p = 0; p < 16; ++p) acc[i][j][p] = 0;

  // prologue: stage tile0 fully + tile1's B; keep B(1) in flight (counted vmcnt)
  ISSUE_A(0, 0, 0); ISSUE_A(0, 0, 1);
  ISSUE_B(0, 0, 0); ISSUE_B(0, 0, 1);
  ISSUE_B(1, 1, 0); ISSUE_B(1, 1, 1);
  asm volatile("s_waitcnt vmcnt(4)" ::: "memory");
  BAR();

  // Per tile t (buf P = t&1), 4 phases of 8 MFMA each (one k-slice of 32):
  //  p1: issue A(t+1)h0 | read b[ks0,ks1](4) + a[ks0](4) | mfma ks0
  //  p2: issue A(t+1)h1 | read b[ks2,ks3](4) + a[ks1](4) | mfma ks1   (B-region fully read)
  //  p3: issue B(t+2)h0 | read a[ks2](4)                 | mfma ks2
  //  p4: issue B(t+2)h1 | read a[ks3](4)                 | mfma ks3 | vmcnt(4) | bar
  // Lifetimes: A(t+1)->bufP^1 A (free since tile t-1 end). B(t+2)->bufP B (ds_reads
  // drained by p2's MFMA lgkm wait + p2-end barrier). vmcnt(4) retires A(t+1), leaves
  // B(t+2) in flight — never drains to 0 in steady state.
#define PH_MFMA(AV, BK) do { \
    acc[0][0] = MFMA32(AV[0], b_[0][BK], acc[0][0]); \
    acc[0][1] = MFMA32(AV[0], b_[1][BK], acc[0][1]); \
    acc[1][0] = MFMA32(AV[1], b_[0][BK], acc[1][0]); \
    acc[1][1] = MFMA32(AV[1], b_[1][BK], acc[1][1]); \
    acc[2][0] = MFMA32(AV[2], b_[0][BK], acc[2][0]); \
    acc[2][1] = MFMA32(AV[2], b_[1][BK], acc[2][1]); \
    acc[3][0] = MFMA32(AV[3], b_[0][BK], acc[3][0]); \
    acc[3][1] = MFMA32(AV[3], b_[1][BK], acc[3][1]); \
  } while (0)

#define KTILE(P, t, DOA, DOB, VM4, VM0) do { \
    i32x4 a_[4], b_[2][4]; \
    /* phase 1 */ \
    if (DOA) ISSUE_A((P) ^ 1, (t) + 1, 0); \
    b_[0][0] = LDB(P, 0, 0); b_[1][0] = LDB(P, 1, 0); \
    b_[0][1] = LDB(P, 0, 1); b_[1][1] = LDB(P, 1, 1); \
    a_[0] = LDA(P, 0, 0); a_[1] = LDA(P, 1, 0); a_[2] = LDA(P, 2, 0); a_[3] = LDA(P, 3, 0); \
    BAR(); __builtin_amdgcn_s_setprio(1); \
    PH_MFMA(a_, 0); \
    __builtin_amdgcn_s_setprio(0); BAR(); \
    /* phase 2 */ \
    if (DOA) ISSUE_A((P) ^ 1, (t) + 1, 1); \
    b_[0][2] = LDB(P, 0, 2); b_[1][2] = LDB(P, 1, 2); \
    b_[0][3] = LDB(P, 0, 3); b_[1][3] = LDB(P, 1, 3); \
    a_[0] = LDA(P, 0, 1); a_[1] = LDA(P, 1, 1); a_[2] = LDA(P, 2, 1); a_[3] = LDA(P, 3, 1); \
    BAR(); __builtin_amdgcn_s_setprio(1); \
    PH_MFMA(a_, 1); \
    __builtin_amdgcn_s_setprio(0); BAR(); \
    /* phase 3 */ \
    if (DOB) ISSUE_B(P, (t) + 2, 0); \
    a_[0] = LDA(P, 0, 2); a_[1] = LDA(P, 1, 2); a_[2] = LDA(P, 2, 2); a_[3] = LDA(P, 3, 2); \
    BAR(); __builtin_amdgcn_s_setprio(1); \
    PH_MFMA(a_, 2); \
    __builtin_amdgcn_s_setprio(0); BAR(); \
    /* phase 4 */ \
    if (DOB) ISSUE_B(P, (t) + 2, 1); \
    a_[0] = LDA(P, 0, 3); a_[1] = LDA(P, 1, 3); a_[2] = LDA(P, 2, 3); a_[3] = LDA(P, 3, 3); \
    BAR(); __builtin_amdgcn_s_setprio(1); \
    PH_MFMA(a_, 3); \
    __builtin_amdgcn_s_setprio(0); \
    if (VM4) asm volatile("s_waitcnt vmcnt(4)" ::: "memory"); \
    if (VM0) asm volatile("s_waitcnt vmcnt(0)" ::: "memory"); \
    BAR(); \
  } while (0)

  for (int it = 0; it < NT / 2 - 1; ++it) {  // t = 0..29
    KTILE(0, 2 * it, 1, 1, 1, 0);
    KTILE(1, 2 * it + 1, 1, 1, 1, 0);
  }
  // tail: t=30 issues A(31) only, drains; t=31 pure consume
  KTILE(0, 30, 1, 0, 0, 1);
  KTILE(1, 31, 0, 0, 0, 0);

  // epilogue: 32x32 C/D layout: col = lane&31, row = (reg&3) + 8*(reg>>2) + 4*(lane>>5)
#pragma unroll
  for (int cj = 0; cj < 2; ++cj) {
    int col = bn * 256 + wc * 64 + cj * 32 + l31;
    float fb = (float)bq[col] * BSCALE;
    int ws = wsum[col];
#pragma unroll
    for (int ri = 0; ri < 4; ++ri) {
      int rb = bm * 256 + wr * 128 + ri * 32 + hi1 * 4;
#pragma unroll
      for (int p = 0; p < 16; ++p) {
        int row = rb + (p & 3) + 8 * (p >> 2);
        out[(size_t)row * Ndim + col] = (float)(acc[ri][cj][p] + ws) * OUT_SCALE + fb;
      }
    }
  }
#undef KTILE
#undef PH_MFMA
#undef ISSUE_A
#undef ISSUE_B
#undef LDA
#undef LDB
}

// ---------------- naive fallback (only if ws_size is unexpectedly small)
__global__ void fallback_kernel(const float* __restrict__ x, const int* __restrict__ wq,
                                const int* __restrict__ bq, float* __restrict__ out) {
  int col = blockIdx.x * 16 + (threadIdx.x & 15);
  int row = blockIdx.y * 16 + (threadIdx.x >> 4);
  const float* xr = x + (size_t)row * Kdim;
  const int* wr_ = wq + (size_t)col * Kdim;
  int acc = 0;
  for (int k = 0; k < Kdim; ++k) {
    int v = (int)rintf(xr[k] / ISF + 127.0f);
    v = v < 0 ? 0 : (v > 255 ? 255 : v);
    acc += (v - 127) * wr_[k];
  }
  out[(size_t)row * Ndim + col] = (float)acc * OUT_SCALE + (float)bq[col] * BSCALE;
}

extern "C" void kernel_launch(void* const* d_in, const int* in_sizes, int n_in,
                              void* d_out, int out_size, void* d_ws, size_t ws_size,
                              hipStream_t stream) {
  const float* x = (const float*)d_in[0];
  const int* wq = (const int*)d_in[1];
  const int* bq = (const int*)d_in[2];
  float* out = (float*)d_out;

  const size_t x8_bytes = (size_t)Mdim * Kdim;  // 32 MiB
  const size_t w8_bytes = (size_t)Ndim * Kdim;  // 16 MiB
  const size_t ws_need = x8_bytes + w8_bytes + (size_t)Ndim * sizeof(int);

  if (ws_size >= ws_need) {
    int8_t* x8 = (int8_t*)d_ws;
    int8_t* w8 = x8 + x8_bytes;
    int* wsum = (int*)(w8 + w8_bytes);

    quantize_x<<<2048, 256, 0, stream>>>(x, (int*)x8, Mdim * Kdim / 4);
    convert_w<<<Ndim, 256, 0, stream>>>(wq, (int*)w8, wsum);
    gemm_i8_32<<<(Mdim / 256) * (Ndim / 256), 512, 0, stream>>>(x8, w8, wsum, bq, out);
  } else {
    dim3 grid(Ndim / 16, Mdim / 16);
    fallback_kernel<<<grid, 256, 0, stream>>>(x, wq, bq, out);
  }
}